// Round 1
// baseline (607.184 us; speedup 1.0000x reference)
//
#include <hip/hip_runtime.h>
#include <math.h>

#define TWO_PI 6.28318530717958647692f
#define SCALE_INV_SQRT_D 0.08838834764831844f   // 1/sqrt(128)

#define NQ 65536
#define NV 131072

// ---------------------------------------------------------------------------
// posmlp_kernel: computes MLP(pos2posemb2d(p)) for 32 rows per block.
// GATE=true additionally computes the SE gate from ctr_feat and multiplies.
// LDS layout:
//   s_a: phase A/B = pe transposed [128][32]; phase D = feat [32][128]
//   s_b: phase B/C = h [32][256];             phase D/E = g1 [32][128]
// ---------------------------------------------------------------------------
template<bool GATE>
__global__ __launch_bounds__(256) void posmlp_kernel(
    const float* __restrict__ ref_pts,      // (!GATE) Q x 3
    const int*   __restrict__ ctr_coor,     // (GATE)  V x 3
    const float* __restrict__ ctr_feat,     // (GATE)  V x 128
    const float* __restrict__ W1, const float* __restrict__ B1,   // 128x256, 256
    const float* __restrict__ W2, const float* __restrict__ B2,   // 256x128, 128
    const float* __restrict__ se_wr, const float* __restrict__ se_br,
    const float* __restrict__ se_we, const float* __restrict__ se_be,
    float* __restrict__ outbuf)             // rows x 128
{
    __shared__ __attribute__((aligned(16))) float s_a[4096];
    __shared__ __attribute__((aligned(16))) float s_b[8192];
    __shared__ float s_px[32], s_py[32], s_dt[32];

    const int t    = threadIdx.x;
    const int row0 = blockIdx.x * 32;

    if (t < 32) {
        // dim_t = 10000^(k/32), match reference's divide
        s_dt[t] = powf(10000.0f, (float)t * (1.0f / 32.0f));
        int row = row0 + t;
        float xx, yy;
        if (GATE) {
            xx = ((float)ctr_coor[row * 3 + 1] + 0.5f) * 0.2f;
            yy = ((float)ctr_coor[row * 3 + 2] + 0.5f) * 0.2f;
        } else {
            xx = ref_pts[row * 3 + 1];
            yy = ref_pts[row * 3 + 2];
        }
        s_px[t] = (xx + 51.2f) / 102.4f * TWO_PI;
        s_py[t] = (yy + 51.2f) / 102.4f * TWO_PI;
    }
    __syncthreads();

    // ---- phase A: positional embedding, stored transposed: s_a[j*32+row]
    // emb[j<64] from y, emb[j>=64] from x; within half: [sin(p/t_k), cos(p/t_k)]
    #pragma unroll
    for (int it = 0; it < 16; ++it) {
        int idx = it * 256 + t;
        int row = idx & 31;
        int j   = idx >> 5;          // 0..127
        int k   = (j >> 1) & 31;
        float p   = (j < 64) ? s_py[row] : s_px[row];
        float ang = p / s_dt[k];
        s_a[j * 32 + row] = (j & 1) ? cosf(ang) : sinf(ang);
    }
    __syncthreads();

    // ---- phase B: h = relu(pe @ W1 + B1)   (32 x 256)
    // thread: cols tx*4..+3 (tx=t&63), rows ty*8..+7 (ty=t>>6)
    {
        const int tx = t & 63, ty = t >> 6;
        float acc[8][4];
        #pragma unroll
        for (int i = 0; i < 8; ++i)
            #pragma unroll
            for (int c = 0; c < 4; ++c) acc[i][c] = 0.f;

        #pragma unroll 2
        for (int k = 0; k < 128; ++k) {
            const float4 w  = *(const float4*)(W1 + k * 256 + tx * 4);
            const float4 a0 = *(const float4*)(s_a + k * 32 + ty * 8);
            const float4 a1 = *(const float4*)(s_a + k * 32 + ty * 8 + 4);
            const float a[8] = {a0.x, a0.y, a0.z, a0.w, a1.x, a1.y, a1.z, a1.w};
            #pragma unroll
            for (int i = 0; i < 8; ++i) {
                acc[i][0] += a[i] * w.x;
                acc[i][1] += a[i] * w.y;
                acc[i][2] += a[i] * w.z;
                acc[i][3] += a[i] * w.w;
            }
        }
        const float4 bb = *(const float4*)(B1 + tx * 4);
        #pragma unroll
        for (int i = 0; i < 8; ++i) {
            float4 hv;
            hv.x = fmaxf(acc[i][0] + bb.x, 0.f);
            hv.y = fmaxf(acc[i][1] + bb.y, 0.f);
            hv.z = fmaxf(acc[i][2] + bb.z, 0.f);
            hv.w = fmaxf(acc[i][3] + bb.w, 0.f);
            *(float4*)(s_b + (ty * 8 + i) * 256 + tx * 4) = hv;
        }
    }
    __syncthreads();

    // ---- phase C: out = h @ W2 + B2   (32 x 128)
    // thread: cols cx*4..+3 (cx=t&31), rows cy*4..+3 (cy=t>>5)
    const int cx = t & 31, cy = t >> 5;
    float outv[4][4];
    {
        float acc[4][4];
        #pragma unroll
        for (int i = 0; i < 4; ++i)
            #pragma unroll
            for (int c = 0; c < 4; ++c) acc[i][c] = 0.f;

        #pragma unroll 4
        for (int k = 0; k < 256; ++k) {
            const float4 w = *(const float4*)(W2 + k * 128 + cx * 4);
            #pragma unroll
            for (int i = 0; i < 4; ++i) {
                const float a = s_b[(cy * 4 + i) * 256 + k];
                acc[i][0] += a * w.x;
                acc[i][1] += a * w.y;
                acc[i][2] += a * w.z;
                acc[i][3] += a * w.w;
            }
        }
        const float4 bb = *(const float4*)(B2 + cx * 4);
        #pragma unroll
        for (int i = 0; i < 4; ++i) {
            outv[i][0] = acc[i][0] + bb.x;
            outv[i][1] = acc[i][1] + bb.y;
            outv[i][2] = acc[i][2] + bb.z;
            outv[i][3] = acc[i][3] + bb.w;
        }
    }

    if (!GATE) {
        #pragma unroll
        for (int i = 0; i < 4; ++i) {
            float4 ov = {outv[i][0], outv[i][1], outv[i][2], outv[i][3]};
            *(float4*)(outbuf + (size_t)(row0 + cy * 4 + i) * 128 + cx * 4) = ov;
        }
        return;
    }

    // ---- gate path ----
    __syncthreads();   // s_a and s_b free for reuse

    // load feat rows into s_a (normal layout [32][128])
    {
        const float4* src = (const float4*)(ctr_feat + (size_t)row0 * 128);
        #pragma unroll
        for (int it = 0; it < 4; ++it)
            ((float4*)s_a)[it * 256 + t] = src[it * 256 + t];
    }
    __syncthreads();

    // ---- phase D: g1 = relu(feat @ se_wr + se_br)  (32 x 128) -> s_b
    {
        float acc[4][4];
        #pragma unroll
        for (int i = 0; i < 4; ++i)
            #pragma unroll
            for (int c = 0; c < 4; ++c) acc[i][c] = 0.f;

        #pragma unroll 4
        for (int k = 0; k < 128; ++k) {
            const float4 w = *(const float4*)(se_wr + k * 128 + cx * 4);
            #pragma unroll
            for (int i = 0; i < 4; ++i) {
                const float a = s_a[(cy * 4 + i) * 128 + k];
                acc[i][0] += a * w.x;
                acc[i][1] += a * w.y;
                acc[i][2] += a * w.z;
                acc[i][3] += a * w.w;
            }
        }
        const float4 bb = *(const float4*)(se_br + cx * 4);
        #pragma unroll
        for (int i = 0; i < 4; ++i) {
            float4 gv;
            gv.x = fmaxf(acc[i][0] + bb.x, 0.f);
            gv.y = fmaxf(acc[i][1] + bb.y, 0.f);
            gv.z = fmaxf(acc[i][2] + bb.z, 0.f);
            gv.w = fmaxf(acc[i][3] + bb.w, 0.f);
            *(float4*)(s_b + (cy * 4 + i) * 128 + cx * 4) = gv;
        }
    }
    __syncthreads();

    // ---- phase E: gate = sigmoid(g1 @ se_we + se_be); out *= gate; store
    {
        float acc[4][4];
        #pragma unroll
        for (int i = 0; i < 4; ++i)
            #pragma unroll
            for (int c = 0; c < 4; ++c) acc[i][c] = 0.f;

        #pragma unroll 4
        for (int k = 0; k < 128; ++k) {
            const float4 w = *(const float4*)(se_we + k * 128 + cx * 4);
            #pragma unroll
            for (int i = 0; i < 4; ++i) {
                const float a = s_b[(cy * 4 + i) * 128 + k];
                acc[i][0] += a * w.x;
                acc[i][1] += a * w.y;
                acc[i][2] += a * w.z;
                acc[i][3] += a * w.w;
            }
        }
        const float4 bb = *(const float4*)(se_be + cx * 4);
        #pragma unroll
        for (int i = 0; i < 4; ++i) {
            float4 ov;
            float g0 = 1.0f / (1.0f + expf(-(acc[i][0] + bb.x)));
            float g1 = 1.0f / (1.0f + expf(-(acc[i][1] + bb.y)));
            float g2 = 1.0f / (1.0f + expf(-(acc[i][2] + bb.z)));
            float g3 = 1.0f / (1.0f + expf(-(acc[i][3] + bb.w)));
            ov.x = outv[i][0] * g0;
            ov.y = outv[i][1] * g1;
            ov.z = outv[i][2] * g2;
            ov.w = outv[i][3] * g3;
            *(float4*)(outbuf + (size_t)(row0 + cy * 4 + i) * 128 + cx * 4) = ov;
        }
    }
}

// ---------------------------------------------------------------------------
// attention: one wave per query; lane l owns elements 2l, 2l+1 of dim 128.
// Dense grid: value index = b*65536 + nx*256 + ny; OOB -> zero row with
// score exactly 0 participating in the softmax denominator.
// ---------------------------------------------------------------------------
__global__ __launch_bounds__(256) void attn_kernel(
    const float* __restrict__ ref_pts,
    const float* __restrict__ qpos,
    const float* __restrict__ vposg,
    const float* __restrict__ ctr_feat,
    float* __restrict__ out)
{
    const int lane = threadIdx.x & 63;
    const int qi   = blockIdx.x * 4 + (threadIdx.x >> 6);

    const int   b = (int)ref_pts[qi * 3 + 0];
    const float x = ref_pts[qi * 3 + 1];
    const float y = ref_pts[qi * 3 + 2];
    // ref_inds = trunc(floor(xy/0.2)/2 + 128); value always >= 0.5 so trunc==floor
    const int xi = (int)(floorf(x / 0.2f) * 0.5f + 128.0f);
    const int yi = (int)(floorf(y / 0.2f) * 0.5f + 128.0f);

    const float2 qv = *(const float2*)(qpos + (size_t)qi * 128 + lane * 2);

    float  sc[9];
    float2 fv[9];
    #pragma unroll
    for (int n = 0; n < 9; ++n) {
        const int nx = xi + n / 3 - 1;
        const int ny = yi + n % 3 - 1;
        const bool valid = ((unsigned)nx < 256u) && ((unsigned)ny < 256u);
        float  s = 0.f;
        float2 f = {0.f, 0.f};
        if (valid) {
            const int idx = (b << 16) + (nx << 8) + ny;
            const float2 v = *(const float2*)(vposg + (size_t)idx * 128 + lane * 2);
            f = *(const float2*)(ctr_feat + (size_t)idx * 128 + lane * 2);
            s = qv.x * v.x + qv.y * v.y;
        }
        sc[n] = s;
        fv[n] = f;
    }

    // butterfly reduce all 9 scores across the 64-lane wave
    #pragma unroll
    for (int off = 32; off > 0; off >>= 1) {
        #pragma unroll
        for (int n = 0; n < 9; ++n)
            sc[n] += __shfl_xor(sc[n], off, 64);
    }

    // softmax over 9 (redundant in every lane)
    float m = -1e30f;
    #pragma unroll
    for (int n = 0; n < 9; ++n) {
        sc[n] *= SCALE_INV_SQRT_D;
        m = fmaxf(m, sc[n]);
    }
    float e[9], denom = 0.f;
    #pragma unroll
    for (int n = 0; n < 9; ++n) {
        e[n] = expf(sc[n] - m);
        denom += e[n];
    }
    const float inv = 1.0f / denom;

    float2 o = {0.f, 0.f};
    #pragma unroll
    for (int n = 0; n < 9; ++n) {
        const float w = e[n] * inv;
        o.x += w * fv[n].x;
        o.y += w * fv[n].y;
    }
    *(float2*)(out + (size_t)qi * 128 + lane * 2) = o;
}

extern "C" void kernel_launch(void* const* d_in, const int* in_sizes, int n_in,
                              void* d_out, int out_size, void* d_ws, size_t ws_size,
                              hipStream_t stream) {
    const float* ref_pts  = (const float*)d_in[0];
    const int*   ctr_coor = (const int*)d_in[1];
    const float* ctr_feat = (const float*)d_in[2];
    const float* q_w1 = (const float*)d_in[3];
    const float* q_b1 = (const float*)d_in[4];
    const float* q_w2 = (const float*)d_in[5];
    const float* q_b2 = (const float*)d_in[6];
    const float* v_w1 = (const float*)d_in[7];
    const float* v_b1 = (const float*)d_in[8];
    const float* v_w2 = (const float*)d_in[9];
    const float* v_b2 = (const float*)d_in[10];
    const float* se_wr = (const float*)d_in[11];
    const float* se_br = (const float*)d_in[12];
    const float* se_we = (const float*)d_in[13];
    const float* se_be = (const float*)d_in[14];

    float* vposg = (float*)d_ws;                       // V*128 floats
    float* qposb = vposg + (size_t)NV * 128;           // Q*128 floats

    posmlp_kernel<false><<<NQ / 32, 256, 0, stream>>>(
        ref_pts, nullptr, nullptr,
        q_w1, q_b1, q_w2, q_b2,
        nullptr, nullptr, nullptr, nullptr, qposb);

    posmlp_kernel<true><<<NV / 32, 256, 0, stream>>>(
        nullptr, ctr_coor, ctr_feat,
        v_w1, v_b1, v_w2, v_b2,
        se_wr, se_br, se_we, se_be, vposg);

    attn_kernel<<<NQ / 4, 256, 0, stream>>>(
        ref_pts, qposb, vposg, ctr_feat, (float*)d_out);
}

// Round 3
// 202.303 us; speedup vs baseline: 3.0014x; 3.0014x over previous
//
#include <hip/hip_runtime.h>
#include <math.h>

#define TWO_PI 6.28318530717958647692f
#define SCALE_INV_SQRT_D 0.08838834764831844f   // 1/sqrt(128)

#define NQ 65536
#define NV 131072

typedef __attribute__((ext_vector_type(8))) short s16x8;
typedef __attribute__((ext_vector_type(4))) float f32x4;

__device__ __forceinline__ unsigned short f2bf(float f) {
    unsigned int u = __builtin_bit_cast(unsigned int, f);
    u += 0x7fffu + ((u >> 16) & 1u);          // round-to-nearest-even
    return (unsigned short)(u >> 16);
}

// ---------------------------------------------------------------------------
// prep: weights -> bf16, transposed to [N][K] so MFMA B-frags are contiguous.
// wbuf layout (ushort): qw1t[256*128] qw2t[128*256] vw1t[256*128] vw2t[128*256]
//                       sewrt[128*128] sewet[128*128]
// ---------------------------------------------------------------------------
__global__ __launch_bounds__(256) void prep_kernel(
    const float* __restrict__ qw1, const float* __restrict__ qw2,
    const float* __restrict__ vw1, const float* __restrict__ vw2,
    const float* __restrict__ sewr, const float* __restrict__ sewe,
    unsigned short* __restrict__ wbuf)
{
    int i = blockIdx.x * 256 + threadIdx.x;   // 163840 total
    const float* src; int K, N, base, li;
    if (i < 32768)       { src = qw1;  K = 128; N = 256; base = 0;      li = i; }
    else if (i < 65536)  { src = qw2;  K = 256; N = 128; base = 32768;  li = i - 32768; }
    else if (i < 98304)  { src = vw1;  K = 128; N = 256; base = 65536;  li = i - 65536; }
    else if (i < 131072) { src = vw2;  K = 256; N = 128; base = 98304;  li = i - 98304; }
    else if (i < 147456) { src = sewr; K = 128; N = 128; base = 131072; li = i - 131072; }
    else                 { src = sewe; K = 128; N = 128; base = 147456; li = i - 147456; }
    int n = li / K, k = li - n * K;
    wbuf[base + li] = f2bf(src[k * N + n]);
}

// ---------------------------------------------------------------------------
// mlp_kernel: 64 rows per block, 4 waves. MFMA 16x16x32 bf16.
// A-frag: row = lane&15, k = (lane>>4)*8+i (k-contiguous)
// B-frag: col = lane&15, k = (lane>>4)*8+i (read from [N][K] transposed wts)
// C/D:    col = lane&15, row = (lane>>4)*4+reg   [m89-verified]
// LDS tiles XOR-swizzled: byte ^= (row&7)<<4 (kills the 16/32-way conflicts
// on stride-256B/512B row-major bf16 tiles, guide §6 G4).
// ---------------------------------------------------------------------------
template<bool GATE>
__global__ __launch_bounds__(256) void mlp_kernel(
    const float* __restrict__ ref_pts,      // (!GATE) Q x 3
    const int*   __restrict__ ctr_coor,     // (GATE)  V x 3
    const float* __restrict__ ctr_feat,     // (GATE)  V x 128
    const unsigned short* __restrict__ w1t, // [256][128] bf16
    const float* __restrict__ b1,
    const unsigned short* __restrict__ w2t, // [128][256] bf16
    const float* __restrict__ b2,
    const unsigned short* __restrict__ sewrt, // [128][128] bf16
    const float* __restrict__ sebr,
    const unsigned short* __restrict__ sewet, // [128][128] bf16
    const float* __restrict__ sebe,
    float* __restrict__ outbuf)
{
    __shared__ __attribute__((aligned(16))) unsigned short s_pe[64 * 128]; // pe / feat
    __shared__ __attribute__((aligned(16))) unsigned short s_h[64 * 256];  // h / g1
    __shared__ float s_p[128];   // px[0:64], py[64:128]

    const int t    = threadIdx.x;
    const int lane = t & 63;
    const int wid  = t >> 6;
    const int row0 = blockIdx.x * 64;
    const int r16  = lane & 15;
    const int g    = lane >> 4;

    // ---- phase 0: positions
    if (t < 64) {
        int row = row0 + t;
        float xx, yy;
        if (GATE) {
            xx = ((float)ctr_coor[row * 3 + 1] + 0.5f) * 0.2f;
            yy = ((float)ctr_coor[row * 3 + 2] + 0.5f) * 0.2f;
        } else {
            xx = ref_pts[row * 3 + 1];
            yy = ref_pts[row * 3 + 2];
        }
        s_p[t]      = (xx + 51.2f) * (TWO_PI / 102.4f);
        s_p[64 + t] = (yy + 51.2f) * (TWO_PI / 102.4f);
    }
    __syncthreads();

    // ---- phase A: positional embedding -> s_pe [64][128] bf16 (swizzled)
    // emb[2i] = sin(p/10000^(i/32)), emb[2i+1] = cos(.), y-half (j<64) then x
    {
        const int row = t >> 2, q = t & 3;
        const float p = s_p[(q < 2 ? 64 : 0) + row];
        unsigned short vals[32];
        #pragma unroll
        for (int kk = 0; kk < 16; ++kk) {
            int k = (q & 1) * 16 + kk;
            float ang = p * __builtin_exp2f((float)k * -0.41524101186092029f); // 1/10000^(k/32)
            float sn, cs;
            __sincosf(ang, &sn, &cs);
            vals[2 * kk]     = f2bf(sn);
            vals[2 * kk + 1] = f2bf(cs);
        }
        #pragma unroll
        for (int c = 0; c < 4; ++c) {
            int byte = row * 256 + q * 64 + c * 16;
            byte ^= (row & 7) << 4;
            *(s16x8*)((char*)s_pe + byte) = *(const s16x8*)(vals + c * 8);
        }
    }
    __syncthreads();

    // ---- phase B: h = relu(pe @ W1 + b1)  (64x256), wave owns 64 cols
    {
        const int col0 = wid * 64;
        f32x4 acc[4][4];
        #pragma unroll
        for (int m = 0; m < 4; ++m)
            #pragma unroll
            for (int n = 0; n < 4; ++n) acc[m][n] = (f32x4)0.f;

        #pragma unroll
        for (int ks = 0; ks < 4; ++ks) {
            s16x8 a[4], b[4];
            #pragma unroll
            for (int m = 0; m < 4; ++m) {
                int row = m * 16 + r16;
                int byte = (row * 256 + ks * 64 + g * 16) ^ ((row & 7) << 4);
                a[m] = *(const s16x8*)((const char*)s_pe + byte);
            }
            #pragma unroll
            for (int n = 0; n < 4; ++n) {
                int wrow = col0 + n * 16 + r16;
                b[n] = *(const s16x8*)(w1t + wrow * 128 + ks * 32 + g * 8);
            }
            #pragma unroll
            for (int m = 0; m < 4; ++m)
                #pragma unroll
                for (int n = 0; n < 4; ++n)
                    acc[m][n] = __builtin_amdgcn_mfma_f32_16x16x32_bf16(a[m], b[n], acc[m][n], 0, 0, 0);
        }
        #pragma unroll
        for (int n = 0; n < 4; ++n) {
            const int col = col0 + n * 16 + r16;
            const float bias = b1[col];
            #pragma unroll
            for (int m = 0; m < 4; ++m)
                #pragma unroll
                for (int r = 0; r < 4; ++r) {
                    int row = m * 16 + g * 4 + r;
                    float v = fmaxf(acc[m][n][r] + bias, 0.f);
                    int byte = (row * 512 + col * 2) ^ ((row & 7) << 4);
                    *(unsigned short*)((char*)s_h + byte) = f2bf(v);
                }
        }
    }
    __syncthreads();

    // ---- phase C: c2 = h @ W2 (64x128), wave owns 32 cols; keep in VGPRs
    f32x4 c2[4][2];
    #pragma unroll
    for (int m = 0; m < 4; ++m)
        #pragma unroll
        for (int n = 0; n < 2; ++n) c2[m][n] = (f32x4)0.f;
    {
        const int col0 = wid * 32;
        #pragma unroll
        for (int ks = 0; ks < 8; ++ks) {
            s16x8 a[4], b[2];
            #pragma unroll
            for (int m = 0; m < 4; ++m) {
                int row = m * 16 + r16;
                int byte = (row * 512 + ks * 64 + g * 16) ^ ((row & 7) << 4);
                a[m] = *(const s16x8*)((const char*)s_h + byte);
            }
            #pragma unroll
            for (int n = 0; n < 2; ++n) {
                int wrow = col0 + n * 16 + r16;
                b[n] = *(const s16x8*)(w2t + wrow * 256 + ks * 32 + g * 8);
            }
            #pragma unroll
            for (int m = 0; m < 4; ++m)
                #pragma unroll
                for (int n = 0; n < 2; ++n)
                    c2[m][n] = __builtin_amdgcn_mfma_f32_16x16x32_bf16(a[m], b[n], c2[m][n], 0, 0, 0);
        }
    }

    if (!GATE) {
        #pragma unroll
        for (int n = 0; n < 2; ++n) {
            const int col = wid * 32 + n * 16 + r16;
            const float bias = b2[col];
            #pragma unroll
            for (int m = 0; m < 4; ++m)
                #pragma unroll
                for (int r = 0; r < 4; ++r) {
                    int row = row0 + m * 16 + g * 4 + r;
                    outbuf[(size_t)row * 128 + col] = c2[m][n][r] + bias;
                }
        }
        return;
    }

    // ---- phase D: feat -> s_pe [64][128] bf16 (swizzled)
    __syncthreads();
    {
        #pragma unroll
        for (int it = 0; it < 8; ++it) {
            int idx = it * 256 + t;          // float4 units, 2048 total
            int row = idx >> 5;
            int c4  = idx & 31;
            f32x4 v = *(const f32x4*)(ctr_feat + (size_t)(row0 + row) * 128 + c4 * 4);
            unsigned short u[4] = {f2bf(v.x), f2bf(v.y), f2bf(v.z), f2bf(v.w)};
            int byte = (row * 256 + c4 * 8) ^ ((row & 7) << 4);
            *(unsigned long long*)((char*)s_pe + byte) = *(const unsigned long long*)u;
        }
    }
    __syncthreads();

    // ---- phase E: g1 = relu(feat @ se_wr + se_br) -> s_h [64][128]
    {
        const int col0 = wid * 32;
        f32x4 acc[4][2];
        #pragma unroll
        for (int m = 0; m < 4; ++m)
            #pragma unroll
            for (int n = 0; n < 2; ++n) acc[m][n] = (f32x4)0.f;
        #pragma unroll
        for (int ks = 0; ks < 4; ++ks) {
            s16x8 a[4], b[2];
            #pragma unroll
            for (int m = 0; m < 4; ++m) {
                int row = m * 16 + r16;
                int byte = (row * 256 + ks * 64 + g * 16) ^ ((row & 7) << 4);
                a[m] = *(const s16x8*)((const char*)s_pe + byte);
            }
            #pragma unroll
            for (int n = 0; n < 2; ++n) {
                int wrow = col0 + n * 16 + r16;
                b[n] = *(const s16x8*)(sewrt + wrow * 128 + ks * 32 + g * 8);
            }
            #pragma unroll
            for (int m = 0; m < 4; ++m)
                #pragma unroll
                for (int n = 0; n < 2; ++n)
                    acc[m][n] = __builtin_amdgcn_mfma_f32_16x16x32_bf16(a[m], b[n], acc[m][n], 0, 0, 0);
        }
        #pragma unroll
        for (int n = 0; n < 2; ++n) {
            const int col = col0 + n * 16 + r16;
            const float bias = sebr[col];
            #pragma unroll
            for (int m = 0; m < 4; ++m)
                #pragma unroll
                for (int r = 0; r < 4; ++r) {
                    int row = m * 16 + g * 4 + r;
                    float v = fmaxf(acc[m][n][r] + bias, 0.f);
                    int byte = (row * 256 + col * 2) ^ ((row & 7) << 4);
                    *(unsigned short*)((char*)s_h + byte) = f2bf(v);
                }
        }
    }
    __syncthreads();

    // ---- phase F: gate = sigmoid(g1 @ se_we + se_be); out = (c2+b2)*gate
    {
        const int col0 = wid * 32;
        f32x4 acc[4][2];
        #pragma unroll
        for (int m = 0; m < 4; ++m)
            #pragma unroll
            for (int n = 0; n < 2; ++n) acc[m][n] = (f32x4)0.f;
        #pragma unroll
        for (int ks = 0; ks < 4; ++ks) {
            s16x8 a[4], b[2];
            #pragma unroll
            for (int m = 0; m < 4; ++m) {
                int row = m * 16 + r16;
                int byte = (row * 256 + ks * 64 + g * 16) ^ ((row & 7) << 4);
                a[m] = *(const s16x8*)((const char*)s_h + byte);
            }
            #pragma unroll
            for (int n = 0; n < 2; ++n) {
                int wrow = col0 + n * 16 + r16;
                b[n] = *(const s16x8*)(sewet + wrow * 128 + ks * 32 + g * 8);
            }
            #pragma unroll
            for (int m = 0; m < 4; ++m)
                #pragma unroll
                for (int n = 0; n < 2; ++n)
                    acc[m][n] = __builtin_amdgcn_mfma_f32_16x16x32_bf16(a[m], b[n], acc[m][n], 0, 0, 0);
        }
        #pragma unroll
        for (int n = 0; n < 2; ++n) {
            const int col = col0 + n * 16 + r16;
            const float b2v = b2[col];
            const float bev = sebe[col];
            #pragma unroll
            for (int m = 0; m < 4; ++m)
                #pragma unroll
                for (int r = 0; r < 4; ++r) {
                    int row = row0 + m * 16 + g * 4 + r;
                    float gate = 1.0f / (1.0f + __expf(-(acc[m][n][r] + bev)));
                    outbuf[(size_t)row * 128 + col] = (c2[m][n][r] + b2v) * gate;
                }
        }
    }
}

// ---------------------------------------------------------------------------
// attention: one wave per query (unchanged from R1 — correct & ~50us)
// ---------------------------------------------------------------------------
__global__ __launch_bounds__(256) void attn_kernel(
    const float* __restrict__ ref_pts,
    const float* __restrict__ qpos,
    const float* __restrict__ vposg,
    const float* __restrict__ ctr_feat,
    float* __restrict__ out)
{
    const int lane = threadIdx.x & 63;
    const int qi   = blockIdx.x * 4 + (threadIdx.x >> 6);

    const int   b = (int)ref_pts[qi * 3 + 0];
    const float x = ref_pts[qi * 3 + 1];
    const float y = ref_pts[qi * 3 + 2];
    const int xi = (int)(floorf(x / 0.2f) * 0.5f + 128.0f);
    const int yi = (int)(floorf(y / 0.2f) * 0.5f + 128.0f);

    const float2 qv = *(const float2*)(qpos + (size_t)qi * 128 + lane * 2);

    float  sc[9];
    float2 fv[9];
    #pragma unroll
    for (int n = 0; n < 9; ++n) {
        const int nx = xi + n / 3 - 1;
        const int ny = yi + n % 3 - 1;
        const bool valid = ((unsigned)nx < 256u) && ((unsigned)ny < 256u);
        float  s = 0.f;
        float2 f = {0.f, 0.f};
        if (valid) {
            const int idx = (b << 16) + (nx << 8) + ny;
            const float2 v = *(const float2*)(vposg + (size_t)idx * 128 + lane * 2);
            f = *(const float2*)(ctr_feat + (size_t)idx * 128 + lane * 2);
            s = qv.x * v.x + qv.y * v.y;
        }
        sc[n] = s;
        fv[n] = f;
    }

    #pragma unroll
    for (int off = 32; off > 0; off >>= 1) {
        #pragma unroll
        for (int n = 0; n < 9; ++n)
            sc[n] += __shfl_xor(sc[n], off, 64);
    }

    float m = -1e30f;
    #pragma unroll
    for (int n = 0; n < 9; ++n) {
        sc[n] *= SCALE_INV_SQRT_D;
        m = fmaxf(m, sc[n]);
    }
    float e[9], denom = 0.f;
    #pragma unroll
    for (int n = 0; n < 9; ++n) {
        e[n] = __expf(sc[n] - m);
        denom += e[n];
    }
    const float inv = 1.0f / denom;

    float2 o = {0.f, 0.f};
    #pragma unroll
    for (int n = 0; n < 9; ++n) {
        const float w = e[n] * inv;
        o.x += w * fv[n].x;
        o.y += w * fv[n].y;
    }
    *(float2*)(out + (size_t)qi * 128 + lane * 2) = o;
}

extern "C" void kernel_launch(void* const* d_in, const int* in_sizes, int n_in,
                              void* d_out, int out_size, void* d_ws, size_t ws_size,
                              hipStream_t stream) {
    const float* ref_pts  = (const float*)d_in[0];
    const int*   ctr_coor = (const int*)d_in[1];
    const float* ctr_feat = (const float*)d_in[2];
    const float* q_w1 = (const float*)d_in[3];
    const float* q_b1 = (const float*)d_in[4];
    const float* q_w2 = (const float*)d_in[5];
    const float* q_b2 = (const float*)d_in[6];
    const float* v_w1 = (const float*)d_in[7];
    const float* v_b1 = (const float*)d_in[8];
    const float* v_w2 = (const float*)d_in[9];
    const float* v_b2 = (const float*)d_in[10];
    const float* se_wr = (const float*)d_in[11];
    const float* se_br = (const float*)d_in[12];
    const float* se_we = (const float*)d_in[13];
    const float* se_be = (const float*)d_in[14];

    unsigned short* wbuf = (unsigned short*)d_ws;                 // 163840 ushort
    float* vposg = (float*)((char*)d_ws + 163840 * 2);            // V*128 f32
    float* qposb = vposg + (size_t)NV * 128;                      // Q*128 f32

    const unsigned short* qw1t  = wbuf;
    const unsigned short* qw2t  = wbuf + 32768;
    const unsigned short* vw1t  = wbuf + 65536;
    const unsigned short* vw2t  = wbuf + 98304;
    const unsigned short* sewrt = wbuf + 131072;
    const unsigned short* sewet = wbuf + 147456;

    prep_kernel<<<640, 256, 0, stream>>>(q_w1, q_w2, v_w1, v_w2, se_wr, se_we, wbuf);

    mlp_kernel<false><<<NQ / 64, 256, 0, stream>>>(
        ref_pts, nullptr, nullptr,
        qw1t, q_b1, qw2t, q_b2,
        nullptr, nullptr, nullptr, nullptr, qposb);

    mlp_kernel<true><<<NV / 64, 256, 0, stream>>>(
        nullptr, ctr_coor, ctr_feat,
        vw1t, v_b1, vw2t, v_b2,
        sewrt, se_br, sewet, se_be, vposg);

    attn_kernel<<<NQ / 4, 256, 0, stream>>>(
        ref_pts, qposb, vposg, ctr_feat, (float*)d_out);
}